// Round 8
// baseline (188.203 us; speedup 1.0000x reference)
//
#include <hip/hip_runtime.h>
#include <hip/hip_bf16.h>
#include <math.h>

#define LEAKY 0.01f
#define B_    2048
#define F_    512
#define H_    64
#define K_    8
#define D_    128
#define ASR_  128
#define MM_   768
#define OUT_  256
#define PROJ_IN 66432          // 128+768+512*128
#define ZK    4992             // 896 + 512*8 (emb folded into proj_w)
#define NSPLIT 8               // gemm split-K factor

// ---------------- workspace layout (bytes) ----------------
// A0   : [B_][896]     bf16   @ 0            3,670,016   (asr|mm pre-bf16)
// Pf   : [F_][B_][8]   bf16   @ 3,670,016   16,777,216   (probs, f-major)
// Wn   : [OUT_][ZK]    bf16   @ 20,447,232   2,555,904
// part : [8][B_][OUT_] fp32   @ 23,003,136  16,777,216
// total 39,780,352

typedef unsigned short u16;
typedef u16   u16x8 __attribute__((ext_vector_type(8)));
typedef short s16x8 __attribute__((ext_vector_type(8)));
typedef float f32x4 __attribute__((ext_vector_type(4)));

__device__ __forceinline__ u16 f2bf(float x) {   // RNE float->bf16 bits
  unsigned int u = __float_as_uint(x);
  u += 0x7fffu + ((u >> 16) & 1u);
  return (u16)(u >> 16);
}

// DPP quad reductions (VALU pipe, NOT the DS pipe). quad_perm codes:
// 0xB1 = [1,0,3,2] (xor1), 0x4E = [2,3,0,1] (xor2).
__device__ __forceinline__ float quad_sum(float g) {
  int a = __builtin_amdgcn_update_dpp(0, __float_as_int(g), 0xB1, 0xF, 0xF, true);
  g += __int_as_float(a);
  int b = __builtin_amdgcn_update_dpp(0, __float_as_int(g), 0x4E, 0xF, 0xF, true);
  return g + __int_as_float(b);
}

__device__ __forceinline__ void ldrow(float4 (&b)[8], const float* p) {
  #pragma unroll
  for (int j = 0; j < 8; ++j) b[j] = *(const float4*)(p + j * 4);
}

__device__ __forceinline__ float dot32(const float4 (&b)[8], const float4 (&e)[8]) {
  float gp0 = 0.f, gp1 = 0.f;
  #pragma unroll
  for (int j = 0; j < 8; ++j) {
    gp0 = fmaf(e[j].x, b[j].x, gp0);
    gp1 = fmaf(e[j].y, b[j].y, gp1);
    gp0 = fmaf(e[j].z, b[j].z, gp0);
    gp1 = fmaf(e[j].w, b[j].w, gp1);
  }
  return gp0 + gp1;
}

// ---------------------------------------------------------------------------
// Fused producers, R4/R0 mixed dispatch order (wn_g first = longest-first).
// THEORY (r0-r5): producer is DS-pipe-bound (~70k DS-cyc/CU shared by wn_g
// broadcasts + probs broadcasts). v5 removes DS traffic:
//   wn_g v5: ZERO LDS / barriers / shfl. Lane (fl,k,dq) global-loads its own
//            32-float pw slice (8 k-lanes share addresses -> L1 broadcast,
//            no L2/HBM amplification); dq-reduce via DPP quad_perm (VALU).
//            Depth-1 row prefetch via two named register buffers.
//   probs  : w2/b2/tau broadcast reads moved to uniform scalar loads
//            (readfirstlane pointer -> SMEM pipe); w1s/b1/s_x stay in LDS.
//   a0    : asr|mm -> bf16 (2048 elems/block)            [unchanged]
//   wn_top: bf16 copy of pw[:, :896] (1024 elems/block)  [unchanged]
#define PRODUCER_BLOCKS (512 + 1024 + 896 + 224)

__global__ __launch_bounds__(256) void producer_kernel(
    const float* __restrict__ stat, const float* __restrict__ w1,
    const float* __restrict__ b1v, const float* __restrict__ w2,
    const float* __restrict__ b2v, const float* __restrict__ tauv,
    const float* __restrict__ pw, const float* __restrict__ emb,
    const float* __restrict__ asr, const float* __restrict__ mm,
    u16* __restrict__ A0, u16* __restrict__ Pf, u16* __restrict__ Wn) {
  __shared__ __align__(16) char smem[15616];
  const int bid = blockIdx.x;
  const int t = threadIdx.x;

  if (bid < 512) {
    // ---------------- wn_g v5 ----------------
    // G[f,k,o] = sum_d emb[f,k,d] * pw[o, 896+f*128+d]
    const int f0 = (bid >> 3) * 8;                    // 64 f-groups of 8
    const int o0 = (bid & 7) * 32;                    // 8 o-chunks of 32
    const int fl = t >> 5, k = (t >> 2) & 7, dq = t & 3;
    // emb fragment in registers: 32 floats (this lane's dq-quarter)
    float4 e[8];
    {
      const float* ep = emb + ((size_t)(f0 + fl) * 8 + k) * 128 + dq * 32;
      #pragma unroll
      for (int j = 0; j < 8; ++j) e[j] = *(const float4*)(ep + j * 4);
    }
    // per-lane global source: its own 32-float slice of each pw row.
    // 8 k-lanes share the address -> one L1 line fetch, broadcast.
    const float* gsrc = pw + 896 + (size_t)(f0 + fl) * 128 + dq * 32
                        + (size_t)o0 * PROJ_IN;
    u16* wdst = Wn + 896 + (size_t)(f0 + fl) * 8 + k;
    float4 bufA[8], bufB[8];
    ldrow(bufA, gsrc);                                // row 0
    #pragma unroll
    for (int rr2 = 0; rr2 < 16; ++rr2) {
      const int r0 = 2 * rr2;
      ldrow(bufB, gsrc + (size_t)(r0 + 1) * PROJ_IN); // prefetch row r0+1
      {
        float g = quad_sum(dot32(bufA, e));
        if (dq == 0) wdst[(size_t)(o0 + r0) * ZK] = f2bf(g);
      }
      if (r0 + 2 < 32)
        ldrow(bufA, gsrc + (size_t)(r0 + 2) * PROJ_IN); // prefetch row r0+2
      {
        float g = quad_sum(dot32(bufB, e));
        if (dq == 0) wdst[(size_t)(o0 + r0 + 1) * ZK] = f2bf(g);
      }
    }
  } else if (bid < 1536) {
    // ---------------- probs: 4 features (1/wave) x 256 rows ----------------
    const int pb = bid - 512;
    const int f0 = (pb & 127) * 4;
    const int b0 = (pb >> 7) * 256;
    float* s_w1s = (float*)(smem);                    // [4][64]   1024 B
    float* s_b1  = (float*)(smem + 1024);             // 1024 B
    float* s_x   = (float*)(smem + 2048);             // 256 rows x stride5 = 5120 B
    {
      int fl = t >> 6, h = t & 63;                    // 256 thr = 4 feat x 64 h
      const float* wf = w1 + (size_t)(f0 + fl) * 192;
      s_w1s[fl * 64 + h] = wf[h] + wf[64 + h] + wf[128 + h];  // x3 identical copies
      s_b1[fl * 64 + h] = b1v[(size_t)(f0 + fl) * 64 + h];
    }
    {
      // stat tile: one float4 per thread (row t, 4 consecutive features)
      float4 sv = *(const float4*)(stat + (size_t)(b0 + t) * F_ + f0);
      float* xr_ = s_x + t * 5;
      xr_[0] = (sv.x >= 0.f) ? sv.x : 0.f;            // NaN -> 0, neg -> 0
      xr_[1] = (sv.y >= 0.f) ? sv.y : 0.f;
      xr_[2] = (sv.z >= 0.f) ? sv.z : 0.f;
      xr_[3] = (sv.w >= 0.f) ? sv.w : 0.f;
    }
    __syncthreads();

    const int w = t >> 6;                             // wave-uniform feature
    const int wu = __builtin_amdgcn_readfirstlane(w); // force SGPR -> s_load path
    const int lane = t & 63;
    const float* w1p = s_w1s + w * 64;
    const float* b1p = s_b1 + w * 64;
    const float* w2u  = w2   + (size_t)(f0 + wu) * 512;   // uniform: SMEM pipe
    const float* b2u  = b2v  + (size_t)(f0 + wu) * 8;
    const float* tauu = tauv + (size_t)(f0 + wu) * 8;
    float x[4];
    #pragma unroll
    for (int p = 0; p < 4; ++p) x[p] = s_x[(lane + 64 * p) * 5 + w];
    float acc[4][8] = {{0.f}};
    #pragma unroll 4
    for (int i = 0; i < 64; ++i) {
      float wv = w1p[i], bv = b1p[i];                 // LDS broadcast (b32)
      float4 wa = *(const float4*)(w2u + i * 8);      // uniform scalar loads
      float4 wb = *(const float4*)(w2u + i * 8 + 4);
      #pragma unroll
      for (int p = 0; p < 4; ++p) {
        float h0 = fmaf(x[p], wv, bv);
        float h = fmaf(LEAKY, fminf(h0, 0.f), fmaxf(h0, 0.f));
        acc[p][0] = fmaf(h, wa.x, acc[p][0]);
        acc[p][1] = fmaf(h, wa.y, acc[p][1]);
        acc[p][2] = fmaf(h, wa.z, acc[p][2]);
        acc[p][3] = fmaf(h, wa.w, acc[p][3]);
        acc[p][4] = fmaf(h, wb.x, acc[p][4]);
        acc[p][5] = fmaf(h, wb.y, acc[p][5]);
        acc[p][6] = fmaf(h, wb.z, acc[p][6]);
        acc[p][7] = fmaf(h, wb.w, acc[p][7]);
      }
    }
    #pragma unroll
    for (int p = 0; p < 4; ++p) {
      float s[K_];
      float m = -1e30f;
      #pragma unroll
      for (int kk = 0; kk < K_; ++kk) {
        float v = acc[p][kk] + b2u[kk];
        v = (v >= 0.f) ? v : LEAKY * v;
        v *= tauu[kk];
        s[kk] = v;
        m = fmaxf(m, v);
      }
      float sum = 0.f;
      #pragma unroll
      for (int kk = 0; kk < K_; ++kk) { s[kk] = __expf(s[kk] - m); sum += s[kk]; }
      float inv = 1.f / sum;
      u16x8 hv;
      #pragma unroll
      for (int kk = 0; kk < K_; ++kk) hv[kk] = f2bf(s[kk] * inv);
      // Pf[f][b][8]: 64 consecutive rows/wave -> coalesced 16B stores
      *(u16x8*)(Pf + ((size_t)(f0 + w) * B_ + b0 + lane + 64 * p) * 8) = hv;
    }
  } else if (bid < 2432) {
    // ---------------- a0: A0[b][j] = bf16(asr|mm) ----------------
    const int item = bid - 1536;                      // 896 blocks x 2048 elems
    const int cidx = item * 256 + t;                  // chunk of 8; 112 chunks/row
    const int r = cidx / 112, c = cidx % 112;
    float4 v0, v1;
    if (c < 16) {
      const float* s = asr + (size_t)r * ASR_ + c * 8;
      v0 = *(const float4*)(s); v1 = *(const float4*)(s + 4);
    } else {
      const float* s = mm + (size_t)r * MM_ + (c - 16) * 8;
      v0 = *(const float4*)(s); v1 = *(const float4*)(s + 4);
    }
    u16x8 hv = {f2bf(v0.x), f2bf(v0.y), f2bf(v0.z), f2bf(v0.w),
                f2bf(v1.x), f2bf(v1.y), f2bf(v1.z), f2bf(v1.w)};
    *(u16x8*)(A0 + (size_t)r * 896 + c * 8) = hv;
  } else {
    // ---------------- wn_top: Wn[o][j] = bf16(pw[o][j]), j<896 ----------------
    const int item = bid - 2432;                      // 224 blocks x 1024 elems
    #pragma unroll
    for (int rr = 0; rr < 4; ++rr) {
      int idx = item * 1024 + rr * 256 + t;           // coalesced
      int o = idx / 896, j = idx % 896;
      Wn[(size_t)o * ZK + j] = f2bf(pw[(size_t)o * PROJ_IN + j]);
    }
  }
}

// ---------------------------------------------------------------------------
// MFMA GEMM, split-K=8: part[kz][b][o] = sum_{k slice} A[b][k]*Wn[o][k]
// BM=64 BN=64 BK=64; LDS 18.4 KB; grid (32,4,8)=1024 blocks.
// Pf staging: 32-lane groups read 512 B contiguous within one plane.
#define SAS 72    // u16 row stride: 144 B
__global__ __launch_bounds__(256) void gemm_kernel(
    const u16* __restrict__ A0, const u16* __restrict__ Pf,
    const u16* __restrict__ Wn, float* __restrict__ part) {
  const int bm0 = blockIdx.x * 64;
  const int bn0 = blockIdx.y * 64;
  const int kz  = blockIdx.z;
  const int it0 = kz * 10;
  const int itn = (kz == 7) ? 8 : 10;                 // 7*10+8 = 78 iters of 64
  __shared__ u16 sA[64 * SAS];                        // 9216 B
  __shared__ u16 sB[64 * SAS];                        // 9216 B
  const int t = threadIdx.x;
  const int w = t >> 6, L = t & 63;
  const int l16 = L & 15, q8 = (L >> 4) * 8;
  const int wm = (w >> 1) * 32, wn = (w & 1) * 32;    // 2x2 wave grid
  const int row = t >> 2, lk = t & 3;                 // A0/Wn staging coords
  const int pp = t >> 5, pg = t & 31;                 // Pf staging coords
  f32x4 acc[2][2] = {{{0.f,0.f,0.f,0.f},{0.f,0.f,0.f,0.f}},
                     {{0.f,0.f,0.f,0.f},{0.f,0.f,0.f,0.f}}};
  u16x8 ra[2], rb[2];

#define LOAD_TILES(IT)                                                        \
  {                                                                           \
    const int k0_ = (IT) * 64;                                                \
    if (k0_ < 896) {                                                          \
      const u16* s_ = A0 + (size_t)(bm0 + row) * 896 + k0_ + lk * 8;          \
      ra[0] = *(const u16x8*)(s_);                                            \
      ra[1] = *(const u16x8*)(s_ + 32);                                       \
    } else {                                                                  \
      const int fb_ = (k0_ - 896) >> 3;                                       \
      const u16* s_ = Pf + ((size_t)(fb_ + pp) * B_ + bm0 + pg) * 8;          \
      ra[0] = *(const u16x8*)(s_);                                            \
      ra[1] = *(const u16x8*)(s_ + 256);   /* +32 rows */                     \
    }                                                                         \
    const u16* sb_ = Wn + (size_t)(bn0 + row) * ZK + k0_ + lk * 8;            \
    rb[0] = *(const u16x8*)(sb_);                                             \
    rb[1] = *(const u16x8*)(sb_ + 32);                                        \
  }

#define STORE_TILES(IT)                                                       \
  {                                                                           \
    if ((IT) * 64 < 896) {                                                    \
      *(u16x8*)&sA[row * SAS + lk * 8]      = ra[0];                          \
      *(u16x8*)&sA[row * SAS + lk * 8 + 32] = ra[1];                          \
    } else {                                                                  \
      *(u16x8*)&sA[pg * SAS + pp * 8]        = ra[0];                         \
      *(u16x8*)&sA[(pg + 32) * SAS + pp * 8] = ra[1];                         \
    }                                                                         \
    *(u16x8*)&sB[row * SAS + lk * 8]      = rb[0];                            \
    *(u16x8*)&sB[row * SAS + lk * 8 + 32] = rb[1];                            \
  }

  LOAD_TILES(it0);
  for (int it = it0; it < it0 + itn; ++it) {
    __syncthreads();
    STORE_TILES(it);
    __syncthreads();
    if (it + 1 < it0 + itn) LOAD_TILES(it + 1);   // overlap next load with MFMA
    #pragma unroll
    for (int ks = 0; ks < 2; ++ks) {
      s16x8 a0 = *(const s16x8*)&sA[(wm + l16) * SAS + ks * 32 + q8];
      s16x8 a1 = *(const s16x8*)&sA[(wm + 16 + l16) * SAS + ks * 32 + q8];
      s16x8 b0 = *(const s16x8*)&sB[(wn + l16) * SAS + ks * 32 + q8];
      s16x8 b1 = *(const s16x8*)&sB[(wn + 16 + l16) * SAS + ks * 32 + q8];
      acc[0][0] = __builtin_amdgcn_mfma_f32_16x16x32_bf16(a0, b0, acc[0][0], 0, 0, 0);
      acc[0][1] = __builtin_amdgcn_mfma_f32_16x16x32_bf16(a0, b1, acc[0][1], 0, 0, 0);
      acc[1][0] = __builtin_amdgcn_mfma_f32_16x16x32_bf16(a1, b0, acc[1][0], 0, 0, 0);
      acc[1][1] = __builtin_amdgcn_mfma_f32_16x16x32_bf16(a1, b1, acc[1][1], 0, 0, 0);
    }
  }
#undef LOAD_TILES
#undef STORE_TILES

  float* dst = part + (size_t)kz * B_ * OUT_;
  #pragma unroll
  for (int mf = 0; mf < 2; ++mf) {
    const int r0 = bm0 + wm + mf * 16 + (L >> 4) * 4;   // C/D: col=lane&15, row=quad*4+i
    #pragma unroll
    for (int nf = 0; nf < 2; ++nf) {
      const int col = bn0 + wn + nf * 16 + l16;
      #pragma unroll
      for (int i = 0; i < 4; ++i)
        dst[(size_t)(r0 + i) * OUT_ + col] = acc[mf][nf][i];
    }
  }
}

// ---------------------------------------------------------------------------
// combine: out = relu(sum_kz part[kz] + bias), float4 per thread
__global__ __launch_bounds__(256) void combine_kernel(
    const float* __restrict__ part, const float* __restrict__ pb,
    float* __restrict__ out) {
  const int idx4 = (blockIdx.x * 256 + threadIdx.x) * 4;
  const int o = idx4 & (OUT_ - 1);
  float4 bv = *(const float4*)(pb + o);
  float4 r = bv;
  #pragma unroll
  for (int kz = 0; kz < NSPLIT; ++kz) {
    float4 a = *(const float4*)(part + (size_t)kz * B_ * OUT_ + idx4);
    r.x += a.x; r.y += a.y; r.z += a.z; r.w += a.w;
  }
  r.x = r.x > 0.f ? r.x : 0.f;
  r.y = r.y > 0.f ? r.y : 0.f;
  r.z = r.z > 0.f ? r.z : 0.f;
  r.w = r.w > 0.f ? r.w : 0.f;
  *(float4*)(out + idx4) = r;
}

// ---------------------------------------------------------------------------
extern "C" void kernel_launch(void* const* d_in, const int* in_sizes, int n_in,
                              void* d_out, int out_size, void* d_ws, size_t ws_size,
                              hipStream_t stream) {
  (void)in_sizes; (void)n_in; (void)out_size; (void)ws_size;
  const float* stat = (const float*)d_in[0];
  const float* asr  = (const float*)d_in[1];
  const float* mm   = (const float*)d_in[2];
  const float* w1   = (const float*)d_in[3];
  const float* b1   = (const float*)d_in[4];
  const float* w2   = (const float*)d_in[5];
  const float* b2   = (const float*)d_in[6];
  const float* tau  = (const float*)d_in[7];
  const float* emb  = (const float*)d_in[8];
  const float* pw   = (const float*)d_in[9];
  const float* pb   = (const float*)d_in[10];
  float* out = (float*)d_out;
  char* ws = (char*)d_ws;
  u16*   A0   = (u16*)(ws);                 //  3,670,016 B
  u16*   Pf   = (u16*)(ws + 3670016);       // 16,777,216 B
  u16*   Wn   = (u16*)(ws + 20447232);      //  2,555,904 B
  float* part = (float*)(ws + 23003136);    // 16,777,216 B

  producer_kernel<<<PRODUCER_BLOCKS, 256, 0, stream>>>(
      stat, w1, b1, w2, b2, tau, pw, emb, asr, mm, A0, Pf, Wn);
  gemm_kernel<<<dim3(B_ / 64, OUT_ / 64, NSPLIT), 256, 0, stream>>>(
      A0, Pf, Wn, part);
  combine_kernel<<<B_ * OUT_ / 1024, 256, 0, stream>>>(part, pb, out);
}

// Round 9
// 157.368 us; speedup vs baseline: 1.1959x; 1.1959x over previous
//
#include <hip/hip_runtime.h>
#include <hip/hip_bf16.h>
#include <math.h>

#define LEAKY 0.01f
#define B_    2048
#define F_    512
#define H_    64
#define K_    8
#define D_    128
#define ASR_  128
#define MM_   768
#define OUT_  256
#define PROJ_IN 66432          // 128+768+512*128
#define ZK    4992             // 896 + 512*8 (emb folded into proj_w)
#define NSPLIT 4               // gemm split-K factor (8->4: halves part traffic)

// ---------------- workspace layout (bytes) ----------------
// A0   : [B_][896]     bf16   @ 0            3,670,016   (asr|mm pre-bf16)
// Pf   : [F_][B_][8]   bf16   @ 3,670,016   16,777,216   (probs, f-major)
// Wn   : [OUT_][ZK]    bf16   @ 20,447,232   2,555,904
// part : [4][B_][OUT_] fp32   @ 23,003,136   8,388,608
// total 31,391,744

typedef unsigned short u16;
typedef u16   u16x8 __attribute__((ext_vector_type(8)));
typedef short s16x8 __attribute__((ext_vector_type(8)));
typedef float f32x4 __attribute__((ext_vector_type(4)));

__device__ __forceinline__ u16 f2bf(float x) {   // RNE float->bf16 bits
  unsigned int u = __float_as_uint(x);
  u += 0x7fffu + ((u >> 16) & 1u);
  return (u16)(u >> 16);
}

// ---------------------------------------------------------------------------
// Fused producers, R0/R4 dispatch order (wn_g first = longest-first).
// v6 = combination of the two VERIFIED best pieces:
//   wn_g  : v3 body (R4, 47.7us run): depth-4 reg prefetch, dbuf LDS, raw
//           s_barrier with lgkmcnt-only drain, quartered conflict-free layout.
//   probs : v5 body (R8, passed): w2/b2/tau via wave-uniform SCALAR loads
//           (SMEM pipe, SGPR~80) -> removes ~41k DS-cyc/CU (the larger DS
//           share); w1s/b1/s_x stay in LDS (cheap b32 broadcasts).
//   a0    : asr|mm -> bf16 (2048 elems/block)            [unchanged]
//   wn_top: bf16 copy of pw[:, :896] (1024 elems/block)  [unchanged]
#define PRODUCER_BLOCKS (512 + 1024 + 896 + 224)
#define QS 40    // quarter stride (32 floats + 8 pad)
#define FS 164   // feature stride = 4*QS + 4 -> fl shifts banks by 4

__global__ __launch_bounds__(256) void producer_kernel(
    const float* __restrict__ stat, const float* __restrict__ w1,
    const float* __restrict__ b1v, const float* __restrict__ w2,
    const float* __restrict__ b2v, const float* __restrict__ tauv,
    const float* __restrict__ pw, const float* __restrict__ emb,
    const float* __restrict__ asr, const float* __restrict__ mm,
    u16* __restrict__ A0, u16* __restrict__ Pf, u16* __restrict__ Wn) {
  __shared__ __align__(16) char smem[15616];
  const int bid = blockIdx.x;
  const int t = threadIdx.x;

  if (bid < 512) {
    // ---------------- wn_g v3 (verified best: R4) ----------------
    // G[f,k,o] = sum_d emb[f,k,d] * pw[o, 896+f*128+d]
    const int f0 = (bid >> 3) * 8;                    // 64 f-groups of 8
    const int o0 = (bid & 7) * 32;                    // 8 o-chunks of 32
    float* s_pw = (float*)smem;                       // [2][8*FS] = 10496 B
    const int fl = t >> 5, k = (t >> 2) & 7, dq = t & 3;
    // emb fragment in registers: 32 floats
    float4 e[8];
    {
      const float* ep = emb + ((size_t)(f0 + fl) * 8 + k) * 128 + dq * 32;
      #pragma unroll
      for (int j = 0; j < 8; ++j) e[j] = *(const float4*)(ep + j * 4);
    }
    // writer: thread t owns float4 #t of the 1024-float row chunk
    const int cq = (t >> 3) & 3, ci = t & 7;
    const int wofs = (t >> 5) * FS + cq * QS + ci * 4;  // quartered layout
    const float* pwbase = pw + 896 + (size_t)f0 * 128 + (size_t)o0 * PROJ_IN + t * 4;
#define LD(R) (*(const float4*)(pwbase + (size_t)(R) * PROJ_IN))
    float4 nx0 = LD(0), nx1 = LD(1), nx2 = LD(2);
    *(float4*)(s_pw + wofs) = nx0;                    // row 0 -> buf0
    nx0 = LD(3);
    asm volatile("s_waitcnt lgkmcnt(0)" ::: "memory");
    __builtin_amdgcn_s_barrier();
    u16* wdst = Wn + (size_t)o0 * ZK + 896 + (size_t)(f0 + fl) * 8 + k;
    for (int r = 0; r < 32; ++r) {
      float* buf  = s_pw + (r & 1) * (8 * FS);
      float* nbuf = s_pw + ((r + 1) & 1) * (8 * FS);
      if (r + 1 < 32) *(float4*)(nbuf + wofs) = nx1;  // row r+1 (load 3 rows old)
      nx1 = nx2; nx2 = nx0;
      if (r + 4 < 32) nx0 = LD(r + 4);                // stays in flight across barrier
      const float* pp = buf + fl * FS + dq * QS;      // banks: fl*4+dq*8 -> all 32
      float gp0 = 0.f, gp1 = 0.f;
      #pragma unroll
      for (int j = 0; j < 8; ++j) {
        float4 p4 = *(const float4*)(pp + j * 4);
        gp0 = fmaf(e[j].x, p4.x, gp0);
        gp1 = fmaf(e[j].y, p4.y, gp1);
        gp0 = fmaf(e[j].z, p4.z, gp0);
        gp1 = fmaf(e[j].w, p4.w, gp1);
      }
      float g = gp0 + gp1;
      g += __shfl_xor(g, 1);                          // reduce over dq
      g += __shfl_xor(g, 2);
      if (dq == 0) wdst[(size_t)r * ZK] = f2bf(g);
      asm volatile("s_waitcnt lgkmcnt(0)" ::: "memory");  // ds ops only; vmcnt NOT drained
      __builtin_amdgcn_s_barrier();
    }
#undef LD
  } else if (bid < 1536) {
    // ---------------- probs v5 (verified: R8): scalar w2/b2/tau ----------------
    const int pb = bid - 512;
    const int f0 = (pb & 127) * 4;
    const int b0 = (pb >> 7) * 256;
    float* s_w1s = (float*)(smem);                    // [4][64]   1024 B
    float* s_b1  = (float*)(smem + 1024);             // 1024 B
    float* s_x   = (float*)(smem + 2048);             // 256 rows x stride5 = 5120 B
    {
      int fl = t >> 6, h = t & 63;                    // 256 thr = 4 feat x 64 h
      const float* wf = w1 + (size_t)(f0 + fl) * 192;
      s_w1s[fl * 64 + h] = wf[h] + wf[64 + h] + wf[128 + h];  // x3 identical copies
      s_b1[fl * 64 + h] = b1v[(size_t)(f0 + fl) * 64 + h];
    }
    {
      // stat tile: one float4 per thread (row t, 4 consecutive features)
      float4 sv = *(const float4*)(stat + (size_t)(b0 + t) * F_ + f0);
      float* xr_ = s_x + t * 5;
      xr_[0] = (sv.x >= 0.f) ? sv.x : 0.f;            // NaN -> 0, neg -> 0
      xr_[1] = (sv.y >= 0.f) ? sv.y : 0.f;
      xr_[2] = (sv.z >= 0.f) ? sv.z : 0.f;
      xr_[3] = (sv.w >= 0.f) ? sv.w : 0.f;
    }
    __syncthreads();

    const int w = t >> 6;                             // wave-uniform feature
    const int wu = __builtin_amdgcn_readfirstlane(w); // force SGPR -> s_load path
    const int lane = t & 63;
    const float* w1p = s_w1s + w * 64;
    const float* b1p = s_b1 + w * 64;
    const float* w2u  = w2   + (size_t)(f0 + wu) * 512;   // uniform: SMEM pipe
    const float* b2u  = b2v  + (size_t)(f0 + wu) * 8;
    const float* tauu = tauv + (size_t)(f0 + wu) * 8;
    float x[4];
    #pragma unroll
    for (int p = 0; p < 4; ++p) x[p] = s_x[(lane + 64 * p) * 5 + w];
    float acc[4][8] = {{0.f}};
    #pragma unroll 4
    for (int i = 0; i < 64; ++i) {
      float wv = w1p[i], bv = b1p[i];                 // LDS broadcast (b32)
      float4 wa = *(const float4*)(w2u + i * 8);      // uniform scalar loads
      float4 wb = *(const float4*)(w2u + i * 8 + 4);
      #pragma unroll
      for (int p = 0; p < 4; ++p) {
        float h0 = fmaf(x[p], wv, bv);
        float h = fmaf(LEAKY, fminf(h0, 0.f), fmaxf(h0, 0.f));
        acc[p][0] = fmaf(h, wa.x, acc[p][0]);
        acc[p][1] = fmaf(h, wa.y, acc[p][1]);
        acc[p][2] = fmaf(h, wa.z, acc[p][2]);
        acc[p][3] = fmaf(h, wa.w, acc[p][3]);
        acc[p][4] = fmaf(h, wb.x, acc[p][4]);
        acc[p][5] = fmaf(h, wb.y, acc[p][5]);
        acc[p][6] = fmaf(h, wb.z, acc[p][6]);
        acc[p][7] = fmaf(h, wb.w, acc[p][7]);
      }
    }
    #pragma unroll
    for (int p = 0; p < 4; ++p) {
      float s[K_];
      float m = -1e30f;
      #pragma unroll
      for (int kk = 0; kk < K_; ++kk) {
        float v = acc[p][kk] + b2u[kk];
        v = (v >= 0.f) ? v : LEAKY * v;
        v *= tauu[kk];
        s[kk] = v;
        m = fmaxf(m, v);
      }
      float sum = 0.f;
      #pragma unroll
      for (int kk = 0; kk < K_; ++kk) { s[kk] = __expf(s[kk] - m); sum += s[kk]; }
      float inv = 1.f / sum;
      u16x8 hv;
      #pragma unroll
      for (int kk = 0; kk < K_; ++kk) hv[kk] = f2bf(s[kk] * inv);
      // Pf[f][b][8]: 64 consecutive rows/wave -> coalesced 16B stores
      *(u16x8*)(Pf + ((size_t)(f0 + w) * B_ + b0 + lane + 64 * p) * 8) = hv;
    }
  } else if (bid < 2432) {
    // ---------------- a0: A0[b][j] = bf16(asr|mm) ----------------
    const int item = bid - 1536;                      // 896 blocks x 2048 elems
    const int cidx = item * 256 + t;                  // chunk of 8; 112 chunks/row
    const int r = cidx / 112, c = cidx % 112;
    float4 v0, v1;
    if (c < 16) {
      const float* s = asr + (size_t)r * ASR_ + c * 8;
      v0 = *(const float4*)(s); v1 = *(const float4*)(s + 4);
    } else {
      const float* s = mm + (size_t)r * MM_ + (c - 16) * 8;
      v0 = *(const float4*)(s); v1 = *(const float4*)(s + 4);
    }
    u16x8 hv = {f2bf(v0.x), f2bf(v0.y), f2bf(v0.z), f2bf(v0.w),
                f2bf(v1.x), f2bf(v1.y), f2bf(v1.z), f2bf(v1.w)};
    *(u16x8*)(A0 + (size_t)r * 896 + c * 8) = hv;
  } else {
    // ---------------- wn_top: Wn[o][j] = bf16(pw[o][j]), j<896 ----------------
    const int item = bid - 2432;                      // 224 blocks x 1024 elems
    #pragma unroll
    for (int rr = 0; rr < 4; ++rr) {
      int idx = item * 1024 + rr * 256 + t;           // coalesced
      int o = idx / 896, j = idx % 896;
      Wn[(size_t)o * ZK + j] = f2bf(pw[(size_t)o * PROJ_IN + j]);
    }
  }
}

// ---------------------------------------------------------------------------
// MFMA GEMM, split-K=4: part[kz][b][o] = sum_{k slice} A[b][k]*Wn[o][k]
// BM=64 BN=64 BK=64; LDS 18.4 KB; grid (32,4,4)=512 blocks, 2/CU.
// Pf staging: 32-lane groups read 512 B contiguous within one plane.
#define SAS 72    // u16 row stride: 144 B
__global__ __launch_bounds__(256) void gemm_kernel(
    const u16* __restrict__ A0, const u16* __restrict__ Pf,
    const u16* __restrict__ Wn, float* __restrict__ part) {
  const int bm0 = blockIdx.x * 64;
  const int bn0 = blockIdx.y * 64;
  const int kz  = blockIdx.z;
  const int it0 = kz * 20;
  const int itn = (kz == 3) ? 18 : 20;                // 3*20+18 = 78 iters of 64
  __shared__ u16 sA[64 * SAS];                        // 9216 B
  __shared__ u16 sB[64 * SAS];                        // 9216 B
  const int t = threadIdx.x;
  const int w = t >> 6, L = t & 63;
  const int l16 = L & 15, q8 = (L >> 4) * 8;
  const int wm = (w >> 1) * 32, wn = (w & 1) * 32;    // 2x2 wave grid
  const int row = t >> 2, lk = t & 3;                 // A0/Wn staging coords
  const int pp = t >> 5, pg = t & 31;                 // Pf staging coords
  f32x4 acc[2][2] = {{{0.f,0.f,0.f,0.f},{0.f,0.f,0.f,0.f}},
                     {{0.f,0.f,0.f,0.f},{0.f,0.f,0.f,0.f}}};
  u16x8 ra[2], rb[2];

#define LOAD_TILES(IT)                                                        \
  {                                                                           \
    const int k0_ = (IT) * 64;                                                \
    if (k0_ < 896) {                                                          \
      const u16* s_ = A0 + (size_t)(bm0 + row) * 896 + k0_ + lk * 8;          \
      ra[0] = *(const u16x8*)(s_);                                            \
      ra[1] = *(const u16x8*)(s_ + 32);                                       \
    } else {                                                                  \
      const int fb_ = (k0_ - 896) >> 3;                                       \
      const u16* s_ = Pf + ((size_t)(fb_ + pp) * B_ + bm0 + pg) * 8;          \
      ra[0] = *(const u16x8*)(s_);                                            \
      ra[1] = *(const u16x8*)(s_ + 256);   /* +32 rows */                     \
    }                                                                         \
    const u16* sb_ = Wn + (size_t)(bn0 + row) * ZK + k0_ + lk * 8;            \
    rb[0] = *(const u16x8*)(sb_);                                             \
    rb[1] = *(const u16x8*)(sb_ + 32);                                        \
  }

#define STORE_TILES(IT)                                                       \
  {                                                                           \
    if ((IT) * 64 < 896) {                                                    \
      *(u16x8*)&sA[row * SAS + lk * 8]      = ra[0];                          \
      *(u16x8*)&sA[row * SAS + lk * 8 + 32] = ra[1];                          \
    } else {                                                                  \
      *(u16x8*)&sA[pg * SAS + pp * 8]        = ra[0];                         \
      *(u16x8*)&sA[(pg + 32) * SAS + pp * 8] = ra[1];                         \
    }                                                                         \
    *(u16x8*)&sB[row * SAS + lk * 8]      = rb[0];                            \
    *(u16x8*)&sB[row * SAS + lk * 8 + 32] = rb[1];                            \
  }

  LOAD_TILES(it0);
  for (int it = it0; it < it0 + itn; ++it) {
    __syncthreads();
    STORE_TILES(it);
    __syncthreads();
    if (it + 1 < it0 + itn) LOAD_TILES(it + 1);   // overlap next load with MFMA
    #pragma unroll
    for (int ks = 0; ks < 2; ++ks) {
      s16x8 a0 = *(const s16x8*)&sA[(wm + l16) * SAS + ks * 32 + q8];
      s16x8 a1 = *(const s16x8*)&sA[(wm + 16 + l16) * SAS + ks * 32 + q8];
      s16x8 b0 = *(const s16x8*)&sB[(wn + l16) * SAS + ks * 32 + q8];
      s16x8 b1 = *(const s16x8*)&sB[(wn + 16 + l16) * SAS + ks * 32 + q8];
      acc[0][0] = __builtin_amdgcn_mfma_f32_16x16x32_bf16(a0, b0, acc[0][0], 0, 0, 0);
      acc[0][1] = __builtin_amdgcn_mfma_f32_16x16x32_bf16(a0, b1, acc[0][1], 0, 0, 0);
      acc[1][0] = __builtin_amdgcn_mfma_f32_16x16x32_bf16(a1, b0, acc[1][0], 0, 0, 0);
      acc[1][1] = __builtin_amdgcn_mfma_f32_16x16x32_bf16(a1, b1, acc[1][1], 0, 0, 0);
    }
  }
#undef LOAD_TILES
#undef STORE_TILES

  float* dst = part + (size_t)kz * B_ * OUT_;
  #pragma unroll
  for (int mf = 0; mf < 2; ++mf) {
    const int r0 = bm0 + wm + mf * 16 + (L >> 4) * 4;   // C/D: col=lane&15, row=quad*4+i
    #pragma unroll
    for (int nf = 0; nf < 2; ++nf) {
      const int col = bn0 + wn + nf * 16 + l16;
      #pragma unroll
      for (int i = 0; i < 4; ++i)
        dst[(size_t)(r0 + i) * OUT_ + col] = acc[mf][nf][i];
    }
  }
}

// ---------------------------------------------------------------------------
// combine: out = relu(sum_kz part[kz] + bias), float4 per thread
__global__ __launch_bounds__(256) void combine_kernel(
    const float* __restrict__ part, const float* __restrict__ pb,
    float* __restrict__ out) {
  const int idx4 = (blockIdx.x * 256 + threadIdx.x) * 4;
  const int o = idx4 & (OUT_ - 1);
  float4 bv = *(const float4*)(pb + o);
  float4 r = bv;
  #pragma unroll
  for (int kz = 0; kz < NSPLIT; ++kz) {
    float4 a = *(const float4*)(part + (size_t)kz * B_ * OUT_ + idx4);
    r.x += a.x; r.y += a.y; r.z += a.z; r.w += a.w;
  }
  r.x = r.x > 0.f ? r.x : 0.f;
  r.y = r.y > 0.f ? r.y : 0.f;
  r.z = r.z > 0.f ? r.z : 0.f;
  r.w = r.w > 0.f ? r.w : 0.f;
  *(float4*)(out + idx4) = r;
}

// ---------------------------------------------------------------------------
extern "C" void kernel_launch(void* const* d_in, const int* in_sizes, int n_in,
                              void* d_out, int out_size, void* d_ws, size_t ws_size,
                              hipStream_t stream) {
  (void)in_sizes; (void)n_in; (void)out_size; (void)ws_size;
  const float* stat = (const float*)d_in[0];
  const float* asr  = (const float*)d_in[1];
  const float* mm   = (const float*)d_in[2];
  const float* w1   = (const float*)d_in[3];
  const float* b1   = (const float*)d_in[4];
  const float* w2   = (const float*)d_in[5];
  const float* b2   = (const float*)d_in[6];
  const float* tau  = (const float*)d_in[7];
  const float* emb  = (const float*)d_in[8];
  const float* pw   = (const float*)d_in[9];
  const float* pb   = (const float*)d_in[10];
  float* out = (float*)d_out;
  char* ws = (char*)d_ws;
  u16*   A0   = (u16*)(ws);                 //  3,670,016 B
  u16*   Pf   = (u16*)(ws + 3670016);       // 16,777,216 B
  u16*   Wn   = (u16*)(ws + 20447232);      //  2,555,904 B
  float* part = (float*)(ws + 23003136);    //  8,388,608 B (NSPLIT=4)

  producer_kernel<<<PRODUCER_BLOCKS, 256, 0, stream>>>(
      stat, w1, b1, w2, b2, tau, pw, emb, asr, mm, A0, Pf, Wn);
  gemm_kernel<<<dim3(B_ / 64, OUT_ / 64, NSPLIT), 256, 0, stream>>>(
      A0, Pf, Wn, part);
  combine_kernel<<<B_ * OUT_ / 1024, 256, 0, stream>>>(part, pb, out);
}